// Round 5
// baseline (357.093 us; speedup 1.0000x reference)
//
#include <hip/hip_runtime.h>

// out = (1/(B*F)) * sum_{i,f} w[cls_i] * (x_if - t_if)^2  +  sum_i pen(t_{i,1})
// B=2e6, F=21, cls_i = t[i*21+2]/100 - 1, pen(v) = (v - clamp(v,0,1000))^2
// R1: global atomics -> serialization (282us). R2: two-stage reduce (120us).
// R3: 4-deep unroll NEUTRAL -- compiler allocated 32 VGPR, serializing loads.
// R4: forced software pipeline: launch_bounds(256,4) (128 VGPR cap), named
//     A/B prefetch sets, exact-residency grid, slimmed inner VALU.
//     (Resubmitted unchanged -- R4 bench died on GPU acquisition timeout.)

#define NVEC 10500000            // (B*F)/4 float4 chunks
#define NBLK 1024                // 4 blocks/CU * 256 CU = exact residency at 16 waves/CU
#define NTHR 256
#define T    (NBLK * NTHR)       // 262144 threads; 40 chunks/thread + 14240-thread tail

struct CH { float4 xf; int4 ti; int tcA, tcB, colA; };

__device__ __forceinline__ void ch_load(int v, const float* __restrict__ x,
                                        const int* __restrict__ t, CH& c)
{
    const int idx0 = v << 2;
    c.xf = reinterpret_cast<const float4*>(x)[v];
    c.ti = reinterpret_cast<const int4*>(t)[v];
    const int rowA = idx0 / 21;                 // magic-mul
    c.colA = idx0 - rowA * 21;
    const int rowB = (idx0 + 3) / 21;
    c.tcA = t[rowA * 21 + 2];                   // L1-hot (same lines as ti loads)
    c.tcB = t[rowB * 21 + 2];
}

__device__ __forceinline__ void ch_compute(const CH& c, const float* ws,
                                           float& am, float& ap)
{
    const float wA = ws[c.tcA / 100 - 1];
    const float wB = ws[c.tcB / 100 - 1];
    const float tf0 = (float)c.ti.x, tf1 = (float)c.ti.y,
                tf2 = (float)c.ti.z, tf3 = (float)c.ti.w;
    const float d0 = c.xf.x - tf0, d1 = c.xf.y - tf1,
                d2 = c.xf.z - tf2, d3 = c.xf.w - tf3;
    const float q0 = d0 * d0, q1 = d1 * d1, q2 = d2 * d2, q3 = d3 * d3;
    // element j is in row B iff j >= k, k = 21-colA (k>=1, so j=0 always row A)
    const int k = 21 - c.colA;
    const float sB = ((1 >= k) ? q1 : 0.f) + ((2 >= k) ? q2 : 0.f)
                   + ((3 >= k) ? q3 : 0.f);
    const float sAll = (q0 + q1) + (q2 + q3);
    am = fmaf(wA, sAll - sB, fmaf(wB, sB, am));
    // penalty element: global col==1 at j = 1-colA (colA<=1) or j = 22-colA (colA>=19)
    const int jp = (c.colA <= 1) ? (1 - c.colA) : (22 - c.colA);
    const float pv = (jp == 0) ? tf0 : (jp == 1) ? tf1 : (jp == 2) ? tf2 : tf3;
    const float r  = pv - fminf(fmaxf(pv, 0.f), 1000.f);
    ap += (jp <= 3) ? r * r : 0.f;
}

__global__ __launch_bounds__(NTHR, 4) void wmse_main(
    const float* __restrict__ x, const int* __restrict__ t,
    const float* __restrict__ w, float* __restrict__ part)
{
    __shared__ float ws[8];
    if (threadIdx.x < 7) ws[threadIdx.x] = w[threadIdx.x];
    __syncthreads();

    const int tid = blockIdx.x * NTHR + threadIdx.x;
    float amA = 0.f, apA = 0.f, amB = 0.f, apB = 0.f;
    CH a0, a1, a2, a3, b0, b1, b2, b3;

    // prologue: set 0 (chunks tid + {0,1,2,3}T)
    ch_load(tid,         x, t, a0);
    ch_load(tid + T,     x, t, a1);
    ch_load(tid + 2 * T, x, t, a2);
    ch_load(tid + 3 * T, x, t, a3);

    int vs = tid;
    #pragma unroll 1
    for (int s = 0; s < 5; ++s) {         // iteration s computes sets 2s, 2s+1
        ch_load(vs + 4 * T, x, t, b0);    // prefetch set 2s+1
        ch_load(vs + 5 * T, x, t, b1);
        ch_load(vs + 6 * T, x, t, b2);
        ch_load(vs + 7 * T, x, t, b3);
        ch_compute(a0, ws, amA, apA); ch_compute(a1, ws, amA, apA);
        ch_compute(a2, ws, amA, apA); ch_compute(a3, ws, amA, apA);
        if (s < 4) {                      // wave-uniform guard
            ch_load(vs + 8 * T,  x, t, a0);   // prefetch set 2s+2
            ch_load(vs + 9 * T,  x, t, a1);
            ch_load(vs + 10 * T, x, t, a2);
            ch_load(vs + 11 * T, x, t, a3);
        }
        ch_compute(b0, ws, amB, apB); ch_compute(b1, ws, amB, apB);
        ch_compute(b2, ws, amB, apB); ch_compute(b3, ws, amB, apB);
        vs += 8 * T;
    }
    // tail: chunks [40T, NVEC) — threads tid < 14240 own one extra chunk
    const int vt = tid + 40 * T;
    if (vt < NVEC) { CH ct; ch_load(vt, x, t, ct); ch_compute(ct, ws, amA, apA); }

    float amain = amA + amB, apen = apA + apB;
    #pragma unroll
    for (int off = 32; off > 0; off >>= 1) {
        amain += __shfl_down(amain, off);
        apen  += __shfl_down(apen,  off);
    }
    __shared__ float rm[4], rp[4];
    const int wid = threadIdx.x >> 6;
    if ((threadIdx.x & 63) == 0) { rm[wid] = amain; rp[wid] = apen; }
    __syncthreads();
    if (threadIdx.x == 0) {
        part[2 * blockIdx.x]     = rm[0] + rm[1] + rm[2] + rm[3];
        part[2 * blockIdx.x + 1] = rp[0] + rp[1] + rp[2] + rp[3];
    }
}

__global__ __launch_bounds__(256) void wmse_reduce(
    const float* __restrict__ part, float* __restrict__ out)
{
    float m = 0.f, p = 0.f;
    for (int i = threadIdx.x; i < NBLK; i += 256) {
        m += part[2 * i];
        p += part[2 * i + 1];
    }
    #pragma unroll
    for (int off = 32; off > 0; off >>= 1) {
        m += __shfl_down(m, off);
        p += __shfl_down(p, off);
    }
    __shared__ float rm[4], rp[4];
    const int wid = threadIdx.x >> 6;
    if ((threadIdx.x & 63) == 0) { rm[wid] = m; rp[wid] = p; }
    __syncthreads();
    if (threadIdx.x == 0) {
        out[0] = (rm[0] + rm[1] + rm[2] + rm[3]) * (1.0f / 42000000.0f)
               + (rp[0] + rp[1] + rp[2] + rp[3]);
    }
}

extern "C" void kernel_launch(void* const* d_in, const int* in_sizes, int n_in,
                              void* d_out, int out_size, void* d_ws, size_t ws_size,
                              hipStream_t stream)
{
    const float* x = (const float*)d_in[0];   // inputs  [B,F] f32
    const int*   t = (const int*)d_in[1];     // targets [B,F] i32
    const float* w = (const float*)d_in[2];   // weights [7]   f32
    float* part = (float*)d_ws;               // 1024*2 floats, all written
    wmse_main<<<NBLK, NTHR, 0, stream>>>(x, t, w, part);
    wmse_reduce<<<1, 256, 0, stream>>>(part, (float*)d_out);
}